// Round 6
// baseline (95.238 us; speedup 1.0000x reference)
//
#include <hip/hip_runtime.h>

#define B_TOTAL 262144
#define K_CB    512
#define D_DIM   3
#define BLOCK   256
#define NBUCK   4096
#define INV_W   512.0f                      // bucket width 1/512 over [-4,4)
#define GUARD   1.9073486328125e-6f         // 2^-19 >> fp32 bucket-rounding err 2^-22

// ---------------- kernel 1: rank codebook + build answer table ---------------
// 12 blocks = 3 dims x 4 quarters. ws: pairs float2[3][512] | ans u32[3][4096].
// ans[t] = lo | cnt<<16 : candidate positions [lo, lo+cnt) in sorted order,
// guaranteed to contain the fp32-exact argmin candidates for every x whose
// computed bucket is t (guard band covers bucket-calc rounding; edge buckets
// forced to cover the open tails).
__global__ __launch_bounds__(BLOCK) void build_kernel(
    const float* __restrict__ e, float2* __restrict__ pairs,
    unsigned int* __restrict__ ans)
{
    const int d   = blockIdx.x >> 2;
    const int q   = blockIdx.x & 3;
    const int tid = threadIdx.x;

    __shared__ float v[K_CB];
    __shared__ float sval[K_CB];

    for (int k = tid; k < K_CB; k += BLOCK) v[k] = e[k * D_DIM + d];
    __syncthreads();

    // stable rank (value, orig idx) + run-head (min idx of equal value)
    const int k0 = tid, k1 = tid + BLOCK;
    const float v0 = v[k0], v1 = v[k1];
    int r0 = 0, r1 = 0, h0 = k0, h1 = k1;
    #pragma unroll 4
    for (int j = 0; j < K_CB; ++j) {
        float vj = v[j];                       // wave-uniform: LDS broadcast
        r0 += (vj < v0 || (vj == v0 && j < k0)) ? 1 : 0;
        r1 += (vj < v1 || (vj == v1 && j < k1)) ? 1 : 0;
        h0  = (vj == v0 && j < h0) ? j : h0;
        h1  = (vj == v1 && j < h1) ? j : h1;
    }
    sval[r0] = v0; sval[r1] = v1;
    if (q == 0) {   // one quarter writes the (val, run-head idx) pairs
        pairs[d * K_CB + r0] = make_float2(v0, __int_as_float(h0));
        pairs[d * K_CB + r1] = make_float2(v1, __int_as_float(h1));
    }
    __syncthreads();

    // build this quarter's 1024 buckets
    const int tbase = q * (NBUCK / 4);
    for (int i = tid; i < NBUCK / 4; i += BLOCK) {
        const int t = tbase + i;
        // exact fp32 edges (ulp 2^-21 grid) with guard band
        const float eL = (-4.0f + (float)t       * (1.0f / INV_W)) - GUARD;
        const float eR = (-4.0f + (float)(t + 1) * (1.0f / INV_W)) + GUARD;

        // count(v <= edge): 10 exact steps over 513 states, clamped mid
        int lo_ = -1, hi_ = K_CB;
        #pragma unroll
        for (int s = 0; s < 10; ++s) {
            int m = (lo_ + hi_) >> 1; m = m < 0 ? 0 : m;
            bool le = sval[m] <= eL;
            lo_ = le ? m : lo_; hi_ = le ? hi_ : m;
        }
        const int cl = lo_ + 1;
        int lo2 = -1, hi2 = K_CB;
        #pragma unroll
        for (int s = 0; s < 10; ++s) {
            int m = (lo2 + hi2) >> 1; m = m < 0 ? 0 : m;
            bool le = sval[m] <= eR;
            lo2 = le ? m : lo2; hi2 = le ? hi2 : m;
        }
        const int cr = lo2 + 1;

        int lo = (t == 0)         ? 0          : (cl > 0 ? cl - 1 : 0);
        int hi = (t == NBUCK - 1) ? (K_CB - 1) : (cr < K_CB ? cr : K_CB - 1);
        ans[d * NBUCK + t] = (unsigned)lo | ((unsigned)(hi - lo + 1) << 16);
    }
}

// ---------------- kernel 2: table lookup + tiny candidate scan ---------------
__global__ __launch_bounds__(BLOCK) void vq_kernel(
    const float* __restrict__ ze, const float2* __restrict__ pairs,
    const unsigned int* __restrict__ ans,
    float* __restrict__ z_out, float* __restrict__ zq_out)
{
    const int b = blockIdx.x * BLOCK + threadIdx.x;
    const float xs[D_DIM] = { ze[b * 3 + 0], ze[b * 3 + 1], ze[b * 3 + 2] };
    float zz[D_DIM], zq[D_DIM];

    #pragma unroll
    for (int d = 0; d < D_DIM; ++d) {
        const float xv = xs[d];
        float tf = floorf((xv + 4.0f) * INV_W);
        tf = fminf(fmaxf(tf, 0.0f), (float)(NBUCK - 1));
        const int t = (int)tf;

        const unsigned a = ans[d * NBUCK + t];     // L2-resident 48 KB table
        const int p   = (int)(a & 0xFFFFu);
        const int cnt = (int)(a >> 16);

        float bd = 3.402823466e38f, bval = 0.0f;
        int bidx = 0x7FFFFFFF;
        for (int i = 0; i < cnt; ++i) {            // avg ~2.2 candidates
            float2 pr = pairs[d * K_CB + p + i];   // L1-resident 12 KB
            float df = xv - pr.x;                  // identical fp32 arith to ref
            float dd = df * df;
            int idx = __float_as_int(pr.y);        // run-head orig index (bit move)
            bool better = (dd < bd) || ((dd == bd) && (idx < bidx));
            bd   = better ? dd  : bd;
            bidx = better ? idx : bidx;
            bval = better ? pr.x : bval;
        }
        zz[d] = (float)bidx; zq[d] = bval;
    }

    z_out [b * 3 + 0] = zz[0]; z_out [b * 3 + 1] = zz[1]; z_out [b * 3 + 2] = zz[2];
    zq_out[b * 3 + 0] = zq[0]; zq_out[b * 3 + 1] = zq[1]; zq_out[b * 3 + 2] = zq[2];
}

extern "C" void kernel_launch(void* const* d_in, const int* in_sizes, int n_in,
                              void* d_out, int out_size, void* d_ws, size_t ws_size,
                              hipStream_t stream) {
    const float* ze = (const float*)d_in[0];
    const float* e  = (const float*)d_in[1];
    float* z_out  = (float*)d_out;                     // z  : B*D float32
    float* zq_out = z_out + (size_t)B_TOTAL * D_DIM;   // zq : B*D float32

    float2*       pairs = (float2*)d_ws;                        // 12 KB
    unsigned int* ans   = (unsigned int*)((char*)d_ws + 12288); // 48 KB

    build_kernel<<<D_DIM * 4,      BLOCK, 0, stream>>>(e, pairs, ans);
    vq_kernel   <<<B_TOTAL / BLOCK, BLOCK, 0, stream>>>(ze, pairs, ans,
                                                        z_out, zq_out);
}

// Round 7
// 94.276 us; speedup vs baseline: 1.0102x; 1.0102x over previous
//
#include <hip/hip_runtime.h>

#define B_TOTAL 262144
#define K_CB    512
#define D_DIM   3
#define BLOCK   256
#define NBUCK   1024
#define BW_INV  128.0f                       // bucket width 2^-7 over [-4,4)
#define GUARD   1.52587890625e-5f            // 2^-16 >> bucket-calc fp32 err ~1e-6

// ---------------- kernel 1: rank codebook + build answer table ---------------
// 6 blocks = 3 dims x 2 halves (halves split the bucket build).
// ws: pairs float2[3][512] | ans u32[3][1024]
// pairs[d][r] = (r-th smallest value, run-head original index)  [(value,idx) order]
// ans[d][t]   = lo | cnt<<16 : sorted-position range guaranteed to contain the
//               fp32-exact argmin candidates for every x whose computed bucket
//               is t (guard band covers bucket rounding; edge buckets cover tails)
__global__ __launch_bounds__(BLOCK) void build_kernel(
    const float* __restrict__ e, float2* __restrict__ pairs,
    unsigned int* __restrict__ ans)
{
    const int d    = blockIdx.x >> 1;
    const int half = blockIdx.x & 1;
    const int tid  = threadIdx.x;

    __shared__ float v[K_CB];
    __shared__ float sval[K_CB];

    for (int k = tid; k < K_CB; k += BLOCK) v[k] = e[k * D_DIM + d];
    __syncthreads();

    // stable rank (value, orig idx) + run-head (min orig idx of equal value)
    const int k0 = tid, k1 = tid + BLOCK;
    const float v0 = v[k0], v1 = v[k1];
    int r0 = 0, r1 = 0, h0 = k0, h1 = k1;
    #pragma unroll 4
    for (int j = 0; j < K_CB; ++j) {
        float vj = v[j];                       // wave-uniform: LDS broadcast
        r0 += (vj < v0 || (vj == v0 && j < k0)) ? 1 : 0;
        r1 += (vj < v1 || (vj == v1 && j < k1)) ? 1 : 0;
        h0  = (vj == v0 && j < h0) ? j : h0;
        h1  = (vj == v1 && j < h1) ? j : h1;
    }
    sval[r0] = v0; sval[r1] = v1;
    if (half == 0) {
        pairs[d * K_CB + r0] = make_float2(v0, __int_as_float(h0));
        pairs[d * K_CB + r1] = make_float2(v1, __int_as_float(h1));
    }
    __syncthreads();

    // this half builds buckets [half*512, half*512+512), 2 per thread
    for (int i = tid; i < NBUCK / 2; i += BLOCK) {
        const int t = half * (NBUCK / 2) + i;
        // edges exact on the 2^-7 fp32 grid; widened by GUARD
        const float eL = (-4.0f + (float)t       * 0.0078125f) - GUARD;
        const float eR = (-4.0f + (float)(t + 1) * 0.0078125f) + GUARD;

        // cl = count(v <= eL): 10 exact steps over 513 states, clamped mid
        int lo_ = -1, hi_ = K_CB;
        #pragma unroll
        for (int s = 0; s < 10; ++s) {
            int m = (lo_ + hi_) >> 1; m = m < 0 ? 0 : m;
            bool le = sval[m] <= eL;
            lo_ = le ? m : lo_; hi_ = le ? hi_ : m;
        }
        const int cl = lo_ + 1;
        // cr = count(v <= eR)
        int lo2 = -1, hi2 = K_CB;
        #pragma unroll
        for (int s = 0; s < 10; ++s) {
            int m = (lo2 + hi2) >> 1; m = m < 0 ? 0 : m;
            bool le = sval[m] <= eR;
            lo2 = le ? m : lo2; hi2 = le ? hi2 : m;
        }
        const int cr = lo2 + 1;

        int lo = (t == 0)         ? 0          : (cl > 0 ? cl - 1 : 0);
        int hi = (t == NBUCK - 1) ? (K_CB - 1) : (cr < K_CB ? cr : K_CB - 1);
        if (hi < lo) hi = lo;                  // never empty (defensive)
        ans[d * NBUCK + t] = (unsigned)lo | ((unsigned)(hi - lo + 1) << 16);
    }
}

// ---------------- kernel 2: LDS table lookup + tiny candidate scan -----------
__global__ __launch_bounds__(BLOCK) void vq_kernel(
    const float* __restrict__ ze, const float2* __restrict__ pairs,
    const unsigned int* __restrict__ ans,
    float* __restrict__ z_out, float* __restrict__ zq_out)
{
    __shared__ float2       sp[D_DIM][K_CB];   // 12 KB
    __shared__ unsigned int sa[D_DIM][NBUCK];  // 12 KB

    const int tid = threadIdx.x;
    {   // vectorized staging from L2-resident 24 KB
        const float4* gp = (const float4*)pairs;  float4* lp = (float4*)sp;
        #pragma unroll
        for (int i = 0; i < 3; ++i) lp[tid + i * BLOCK] = gp[tid + i * BLOCK];
        const uint4* ga = (const uint4*)ans;      uint4* la = (uint4*)sa;
        #pragma unroll
        for (int i = 0; i < 3; ++i) la[tid + i * BLOCK] = ga[tid + i * BLOCK];
    }
    __syncthreads();

    const int b = blockIdx.x * BLOCK + tid;
    const float xs[D_DIM] = { ze[b * 3 + 0], ze[b * 3 + 1], ze[b * 3 + 2] };
    float zz[D_DIM], zq[D_DIM];

    #pragma unroll
    for (int d = 0; d < D_DIM; ++d) {
        const float xv = xs[d];
        float tf = floorf((xv + 4.0f) * BW_INV);
        tf = fminf(fmaxf(tf, 0.0f), (float)(NBUCK - 1));
        const int t = (int)tf;

        const unsigned a = sa[d][t];           // 1 divergent LDS read
        const int p   = (int)(a & 0xFFFFu);
        const int cnt = (int)(a >> 16);

        float bd = 3.402823466e38f, bval = 0.0f;
        int bidx = 0x7FFFFFFF;
        for (int i = 0; i < cnt; ++i) {        // avg ~3 candidates, LDS b64 reads
            float2 pr = sp[d][p + i];
            float df = xv - pr.x;              // identical fp32 arith to ref
            float dd = df * df;
            int idx = __float_as_int(pr.y);    // run-head orig index (bit move)
            bool better = (dd < bd) || ((dd == bd) && (idx < bidx));
            bd   = better ? dd  : bd;
            bidx = better ? idx : bidx;
            bval = better ? pr.x : bval;
        }
        zz[d] = (float)bidx; zq[d] = bval;
    }

    z_out [b * 3 + 0] = zz[0]; z_out [b * 3 + 1] = zz[1]; z_out [b * 3 + 2] = zz[2];
    zq_out[b * 3 + 0] = zq[0]; zq_out[b * 3 + 1] = zq[1]; zq_out[b * 3 + 2] = zq[2];
}

extern "C" void kernel_launch(void* const* d_in, const int* in_sizes, int n_in,
                              void* d_out, int out_size, void* d_ws, size_t ws_size,
                              hipStream_t stream) {
    const float* ze = (const float*)d_in[0];
    const float* e  = (const float*)d_in[1];
    float* z_out  = (float*)d_out;                     // z  : B*D float32
    float* zq_out = z_out + (size_t)B_TOTAL * D_DIM;   // zq : B*D float32

    float2*       pairs = (float2*)d_ws;                        // 12 KB
    unsigned int* ans   = (unsigned int*)((char*)d_ws + 12288); // 12 KB

    build_kernel<<<D_DIM * 2,       BLOCK, 0, stream>>>(e, pairs, ans);
    vq_kernel   <<<B_TOTAL / BLOCK, BLOCK, 0, stream>>>(ze, pairs, ans,
                                                        z_out, zq_out);
}

// Round 8
// 70.951 us; speedup vs baseline: 1.3423x; 1.3287x over previous
//
#include <hip/hip_runtime.h>

#define B_TOTAL 262144
#define K_CB    512
#define D_DIM   3
#define BLOCK   256

// monotone map fp32 bits -> uint32 (ascending float => ascending uint)
__device__ __forceinline__ unsigned int mono32(unsigned int u) {
    unsigned int m = (u & 0x80000000u) ? 0xFFFFFFFFu : 0x80000000u;
    return u ^ m;
}

// ---------------- kernel 1: rank-sort the tiny codebook into d_ws -------------
// grid = D_DIM * 2 blocks; block (d, half) ranks entries [half*256, half*256+256)
// of dim d. ws layout: sval[3][512] floats, then sidx[3][512] ints.
__global__ __launch_bounds__(BLOCK) void rank_kernel(
    const float* __restrict__ e, float* __restrict__ ws_val, int* __restrict__ ws_idx)
{
    const int d    = blockIdx.x >> 1;
    const int half = blockIdx.x & 1;
    const int tid  = threadIdx.x;

    __shared__ unsigned long long key[K_CB];
    __shared__ float              val[K_CB];

    for (int k = tid; k < K_CB; k += BLOCK) {
        float v = e[k * D_DIM + d];
        key[k] = ((unsigned long long)mono32(__float_as_uint(v)) << 32) | (unsigned int)k;
        val[k] = v;
    }
    __syncthreads();

    const int i = half * BLOCK + tid;           // my entry
    const unsigned long long mykey = key[i];
    int rank = 0;
    #pragma unroll 8
    for (int j = 0; j < K_CB; ++j)              // wave-uniform LDS reads: broadcast
        rank += (key[j] < mykey) ? 1 : 0;

    ws_val[d * K_CB + rank] = val[i];
    ws_idx[d * K_CB + rank] = i;
}

// ---------------- kernel 2: binary search over sorted codebook ----------------
__global__ __launch_bounds__(BLOCK) void vq_search_kernel(
    const float* __restrict__ ze,
    const float* __restrict__ ws_val, const int* __restrict__ ws_idx,
    float* __restrict__ z_out, float* __restrict__ zq_out)
{
    __shared__ float sval[D_DIM][K_CB];   // 6 KB
    __shared__ int   sidx[D_DIM][K_CB];   // 6 KB

    const int tid = threadIdx.x;
    {   // vectorized staging (delta vs R4: float4/int4 instead of scalar)
        const float4* gv = (const float4*)ws_val; float4* lv = (float4*)sval;
        for (int i = tid; i < D_DIM * K_CB / 4; i += BLOCK) lv[i] = gv[i];
        const int4*   gi = (const int4*)ws_idx;   int4*   li = (int4*)sidx;
        for (int i = tid; i < D_DIM * K_CB / 4; i += BLOCK) li[i] = gi[i];
    }
    __syncthreads();

    const int b = blockIdx.x * BLOCK + tid;
    const float xs[D_DIM] = { ze[b * 3 + 0], ze[b * 3 + 1], ze[b * 3 + 2] };

    #pragma unroll
    for (int d = 0; d < D_DIM; ++d) {
        const float xv = xs[d];

        // binary search: invariant sval[lo] <= xv < sval[hi] (virtual sentinels)
        // 10 iterations fully resolve the 513-state interval (delta vs R4's 9;
        // mid stays in [0,511]: interval length is >=2 at every iteration)
        int lo = -1, hi = K_CB;
        #pragma unroll
        for (int it = 0; it < 10; ++it) {
            int mid = (lo + hi) >> 1;
            bool le = sval[d][mid] <= xv;
            lo = le ? mid : lo;
            hi = le ? hi : mid;
        }

        // left candidate: walk back to first entry of the equal-value run
        // (sorted by (value,idx) => that's the min original index)
        float dl = 3.402823466e38f, vl = 0.0f; int il = 0;
        if (lo >= 0) {
            vl = sval[d][lo];
            int p = lo;
            while (p > 0 && sval[d][p - 1] == vl) --p;   // exact-duplicate handling
            il = sidx[d][p];
            float t = xv - vl;                  // identical fp32 arithmetic to ref
            dl = t * t;
        }
        // right candidate: nearest value > xv (group head == lo+1 by construction)
        float dr = 3.402823466e38f, vr = 0.0f; int ir = 0;
        if (lo < K_CB - 1) {
            vr = sval[d][lo + 1];
            ir = sidx[d][lo + 1];
            float t = xv - vr;
            dr = t * t;
        }

        // np.argmin semantics: strict min; tie -> smaller original index
        const bool pickR = (dr < dl) || ((dr == dl) && (ir < il));
        z_out [b * 3 + d] = (float)(pickR ? ir : il);
        zq_out[b * 3 + d] = pickR ? vr : vl;
    }
}

extern "C" void kernel_launch(void* const* d_in, const int* in_sizes, int n_in,
                              void* d_out, int out_size, void* d_ws, size_t ws_size,
                              hipStream_t stream) {
    const float* ze = (const float*)d_in[0];
    const float* e  = (const float*)d_in[1];
    float* z_out  = (float*)d_out;                    // z  : B*D float32
    float* zq_out = z_out + (size_t)B_TOTAL * D_DIM;  // zq : B*D float32

    float* ws_val = (float*)d_ws;                     // [3][512] sorted values
    int*   ws_idx = (int*)(ws_val + D_DIM * K_CB);    // [3][512] original indices

    rank_kernel     <<<D_DIM * 2,       BLOCK, 0, stream>>>(e, ws_val, ws_idx);
    vq_search_kernel<<<B_TOTAL / BLOCK, BLOCK, 0, stream>>>(ze, ws_val, ws_idx,
                                                            z_out, zq_out);
}